// Round 1
// baseline (873.966 us; speedup 1.0000x reference)
//
#include <hip/hip_runtime.h>
#include <hip/hip_bf16.h>
#include <stdint.h>

typedef __attribute__((ext_vector_type(8))) short short8;
typedef __attribute__((ext_vector_type(4))) float floatx4;

#define MFMA16(a, b, c) __builtin_amdgcn_mfma_f32_16x16x32_bf16(a, b, c, 0, 0, 0)

constexpr int N_Q  = 8192;
constexpr int M_KV = 8192;
constexpr int DMID = 128;
constexpr int DV   = 256;

__device__ __forceinline__ unsigned short f2bf(float x) {
    unsigned u = __float_as_uint(x);
    u += 0x7fffu + ((u >> 16) & 1u);
    return (unsigned short)(u >> 16);
}

__device__ __forceinline__ short8 cvt_f8_bf8(float4 a, float4 b) {
    short8 r;
    r[0] = (short)f2bf(a.x); r[1] = (short)f2bf(a.y);
    r[2] = (short)f2bf(a.z); r[3] = (short)f2bf(a.w);
    r[4] = (short)f2bf(b.x); r[5] = (short)f2bf(b.y);
    r[6] = (short)f2bf(b.z); r[7] = (short)f2bf(b.w);
    return r;
}

// ---------------------------------------------------------------------------
// Mask dtype detection: 0 = int32 {0,1}, 1 = uint8 {0,1}, 2 = float32 {0,1}
// Packed uint8 words look like 0x01010001 (>1); float words are 0x3f800000.
// ---------------------------------------------------------------------------
__global__ void detect_mask_kernel(const unsigned int* __restrict__ mw, int* __restrict__ flag) {
    int t = threadIdx.x;
    unsigned w = mw[t];
    bool isf = (w == 0x3f800000u);
    bool isb = (w > 1u) && !isf;
    unsigned long long bf = __ballot(isf);
    unsigned long long bb = __ballot(isb);
    if (t == 0) *flag = bf ? 2 : (bb ? 1 : 0);
}

// ---------------------------------------------------------------------------
// Projections: dst[row,0:128] = src[row,0:256] @ W[128,256]^T + bias, bf16 out.
// blockIdx.y = 0 -> Q (main,Wq,bq), 1 -> K (other,Wk,bk). 4 waves x 16 rows.
// ---------------------------------------------------------------------------
__global__ __launch_bounds__(256) void proj_kernel(
    const float* __restrict__ main_feat, const float* __restrict__ Wq, const float* __restrict__ bq,
    const float* __restrict__ other_feat, const float* __restrict__ Wk, const float* __restrict__ bk,
    unsigned short* __restrict__ Qw, unsigned short* __restrict__ Kw)
{
    const float* src;  const float* W;  const float* bias;  unsigned short* dst;
    if (blockIdx.y == 0) { src = main_feat;  W = Wq; bias = bq; dst = Qw; }
    else                 { src = other_feat; W = Wk; bias = bk; dst = Kw; }

    const int wave = threadIdx.x >> 6, lane = threadIdx.x & 63;
    const int n = lane & 15, quad = lane >> 4;
    const int row0 = blockIdx.x * 64 + wave * 16;

    short8 a[8];
    const float* ap = src + (size_t)(row0 + n) * 256 + quad * 8;
#pragma unroll
    for (int ks = 0; ks < 8; ++ks) {
        float4 x0 = *(const float4*)(ap + ks * 32);
        float4 x1 = *(const float4*)(ap + ks * 32 + 4);
        a[ks] = cvt_f8_bf8(x0, x1);
    }

    floatx4 acc[8];
#pragma unroll
    for (int nt = 0; nt < 8; ++nt) acc[nt] = floatx4{0.f, 0.f, 0.f, 0.f};

#pragma unroll
    for (int nt = 0; nt < 8; ++nt) {
        const float* wp = W + (size_t)(nt * 16 + n) * 256 + quad * 8;
#pragma unroll
        for (int ks = 0; ks < 8; ++ks) {
            float4 w0 = *(const float4*)(wp + ks * 32);
            float4 w1 = *(const float4*)(wp + ks * 32 + 4);
            short8 b = cvt_f8_bf8(w0, w1);
            acc[nt] = MFMA16(a[ks], b, acc[nt]);
        }
    }

#pragma unroll
    for (int nt = 0; nt < 8; ++nt) {
        float bb = bias[nt * 16 + n];
#pragma unroll
        for (int reg = 0; reg < 4; ++reg) {
            int r = row0 + quad * 4 + reg;
            dst[(size_t)r * DMID + nt * 16 + n] = f2bf(acc[nt][reg] + bb);
        }
    }
}

// ---------------------------------------------------------------------------
// Vt[d][m] = fix[m] * other[m][d], bf16, transposed so PV B-frags are
// contiguous. 64x64 tiles via LDS.
// ---------------------------------------------------------------------------
__global__ __launch_bounds__(256) void build_vt_kernel(
    const float* __restrict__ other_feat, const float* __restrict__ fix_feat,
    unsigned short* __restrict__ Vt)
{
    __shared__ unsigned short tile[64 * 72];   // [d_local][m_local], stride 72
    const int t = threadIdx.x;
    const int m0 = blockIdx.x * 64, d0 = blockIdx.y * 64;

#pragma unroll
    for (int r = 0; r < 4; ++r) {
        int idx = r * 256 + t;
        int ml = idx >> 4, dl4 = (idx & 15) * 4;
        float4 v = *(const float4*)(other_feat + (size_t)(m0 + ml) * 256 + d0 + dl4);
        float f = fix_feat[m0 + ml];
        tile[(dl4 + 0) * 72 + ml] = f2bf(v.x * f);
        tile[(dl4 + 1) * 72 + ml] = f2bf(v.y * f);
        tile[(dl4 + 2) * 72 + ml] = f2bf(v.z * f);
        tile[(dl4 + 3) * 72 + ml] = f2bf(v.w * f);
    }
    __syncthreads();
#pragma unroll
    for (int r = 0; r < 8; ++r) {
        int dl = r * 8 + (t >> 5);
        int ml = (t & 31) * 2;
        unsigned int v0 = tile[dl * 72 + ml];
        unsigned int v1 = tile[dl * 72 + ml + 1];
        *(unsigned int*)(Vt + (size_t)(d0 + dl) * M_KV + m0 + ml) = v0 | (v1 << 16);
    }
}

// ---------------------------------------------------------------------------
// Flash attention with split-K over M. Block: 256 thr (4 waves x 32 Q rows),
// BM=128, BN=64. 16x16x32 bf16 MFMA. Writes unnormalized partials + (m,l).
// All logits in log2 domain; masked logits = -3e30 (finite -> reproduces the
// reference's -(1<<32) masked_fill semantics incl. all-masked rows).
// ---------------------------------------------------------------------------
__global__ __launch_bounds__(256) void flash_kernel(
    const unsigned short* __restrict__ Qw, const unsigned short* __restrict__ Kw,
    const unsigned short* __restrict__ Vt, const void* __restrict__ mask,
    const int* __restrict__ flagp,
    float* __restrict__ Opart, float* __restrict__ Mpart, float* __restrict__ Lpart,
    int nsplit)
{
    __shared__ __align__(16) unsigned short k_lds[64 * 136];   // [kv_row][mid], stride 136
    __shared__ __align__(16) unsigned short vt_lds[256 * 72];  // [d][m_local], stride 72
    __shared__ __align__(16) unsigned short p_lds[4][32 * 72]; // per-wave P, stride 72

    const int chunkLen = M_KV / nsplit;
    const int mBeg = blockIdx.y * chunkLen;
    const int tid = threadIdx.x;
    const int wave = tid >> 6, lane = tid & 63, n = lane & 15, quad = lane >> 4;
    const int qrow0 = blockIdx.x * 128 + wave * 32;
    const int mflag = *flagp;
    constexpr float SC = 0.08838834764831845f * 1.4426950408889634f; // scale*log2(e)
    constexpr float MASKV = -3.0e30f;

    short8 qf[2][4];
#pragma unroll
    for (int rt = 0; rt < 2; ++rt)
#pragma unroll
        for (int ks = 0; ks < 4; ++ks)
            qf[rt][ks] = *(const short8*)(Qw + (size_t)(qrow0 + rt * 16 + n) * DMID + ks * 32 + quad * 8);

    floatx4 Oacc[2][16];
#pragma unroll
    for (int rt = 0; rt < 2; ++rt)
#pragma unroll
        for (int dt = 0; dt < 16; ++dt) Oacc[rt][dt] = floatx4{0.f, 0.f, 0.f, 0.f};

    float mrow[2][4], lrow[2][4];
#pragma unroll
    for (int rt = 0; rt < 2; ++rt)
#pragma unroll
        for (int reg = 0; reg < 4; ++reg) { mrow[rt][reg] = -__builtin_inff(); lrow[rt][reg] = 0.f; }

    const int iters = chunkLen / 64;
    for (int it = 0; it < iters; ++it) {
        const int m0 = mBeg + it * 64;
        __syncthreads();
        // stage K tile: 64 rows x 128 mid (16B chunks)
#pragma unroll
        for (int r = 0; r < 4; ++r) {
            int idx = r * 256 + tid; int kr = idx >> 4, kc = idx & 15;
            *(short8*)&k_lds[kr * 136 + kc * 8] =
                *(const short8*)(Kw + (size_t)(m0 + kr) * DMID + kc * 8);
        }
        // stage Vt tile: 256 d-rows x 64 m
#pragma unroll
        for (int r = 0; r < 8; ++r) {
            int idx = r * 256 + tid; int vr = idx >> 3, vc = idx & 7;
            *(short8*)&vt_lds[vr * 72 + vc * 8] =
                *(const short8*)(Vt + (size_t)vr * M_KV + m0 + vc * 8);
        }
        __syncthreads();

        // ---- S = Q K^T  (per wave: [32 x 64]) ----
        floatx4 S[2][4];
#pragma unroll
        for (int rt = 0; rt < 2; ++rt)
#pragma unroll
            for (int nt = 0; nt < 4; ++nt) S[rt][nt] = floatx4{0.f, 0.f, 0.f, 0.f};

#pragma unroll
        for (int nt = 0; nt < 4; ++nt) {
            const int kb = (nt * 16 + n) * 136 + quad * 8;
            short8 b0 = *(const short8*)&k_lds[kb];
            short8 b1 = *(const short8*)&k_lds[kb + 32];
            short8 b2 = *(const short8*)&k_lds[kb + 64];
            short8 b3 = *(const short8*)&k_lds[kb + 96];
            S[0][nt] = MFMA16(qf[0][0], b0, S[0][nt]);
            S[0][nt] = MFMA16(qf[0][1], b1, S[0][nt]);
            S[0][nt] = MFMA16(qf[0][2], b2, S[0][nt]);
            S[0][nt] = MFMA16(qf[0][3], b3, S[0][nt]);
            S[1][nt] = MFMA16(qf[1][0], b0, S[1][nt]);
            S[1][nt] = MFMA16(qf[1][1], b1, S[1][nt]);
            S[1][nt] = MFMA16(qf[1][2], b2, S[1][nt]);
            S[1][nt] = MFMA16(qf[1][3], b3, S[1][nt]);
        }

        // ---- mask (uniform branch on detected dtype) ----
        unsigned mbits = 0;
        if (mflag == 0) {
            const int* mp = (const int*)mask;
            int bit = 0;
#pragma unroll
            for (int rt = 0; rt < 2; ++rt)
#pragma unroll
                for (int nt = 0; nt < 4; ++nt)
#pragma unroll
                    for (int reg = 0; reg < 4; ++reg) {
                        size_t mi = (size_t)(qrow0 + rt * 16 + quad * 4 + reg) * M_KV + (m0 + nt * 16 + n);
                        mbits |= (unsigned)(mp[mi] != 0) << bit; ++bit;
                    }
        } else if (mflag == 1) {
            const unsigned char* mp = (const unsigned char*)mask;
            int bit = 0;
#pragma unroll
            for (int rt = 0; rt < 2; ++rt)
#pragma unroll
                for (int nt = 0; nt < 4; ++nt)
#pragma unroll
                    for (int reg = 0; reg < 4; ++reg) {
                        size_t mi = (size_t)(qrow0 + rt * 16 + quad * 4 + reg) * M_KV + (m0 + nt * 16 + n);
                        mbits |= (unsigned)(mp[mi] != 0) << bit; ++bit;
                    }
        } else {
            const float* mp = (const float*)mask;
            int bit = 0;
#pragma unroll
            for (int rt = 0; rt < 2; ++rt)
#pragma unroll
                for (int nt = 0; nt < 4; ++nt)
#pragma unroll
                    for (int reg = 0; reg < 4; ++reg) {
                        size_t mi = (size_t)(qrow0 + rt * 16 + quad * 4 + reg) * M_KV + (m0 + nt * 16 + n);
                        mbits |= (unsigned)(mp[mi] != 0.f) << bit; ++bit;
                    }
        }
        {
            int bit = 0;
#pragma unroll
            for (int rt = 0; rt < 2; ++rt)
#pragma unroll
                for (int nt = 0; nt < 4; ++nt)
#pragma unroll
                    for (int reg = 0; reg < 4; ++reg) {
                        float s = S[rt][nt][reg];
                        S[rt][nt][reg] = ((mbits >> bit) & 1u) ? MASKV : s * SC;
                        ++bit;
                    }
        }

        // ---- online softmax (rows = quad*4+reg; cols spread over 16 lanes) ----
#pragma unroll
        for (int rt = 0; rt < 2; ++rt) {
            float mnew[4], alpha[4];
#pragma unroll
            for (int reg = 0; reg < 4; ++reg) {
                float v = fmaxf(fmaxf(S[rt][0][reg], S[rt][1][reg]),
                                fmaxf(S[rt][2][reg], S[rt][3][reg]));
                v = fmaxf(v, __shfl_xor(v, 1));
                v = fmaxf(v, __shfl_xor(v, 2));
                v = fmaxf(v, __shfl_xor(v, 4));
                v = fmaxf(v, __shfl_xor(v, 8));
                mnew[reg] = fmaxf(mrow[rt][reg], v);
                alpha[reg] = exp2f(mrow[rt][reg] - mnew[reg]);
                mrow[rt][reg] = mnew[reg];
            }
            float rs[4] = {0.f, 0.f, 0.f, 0.f};
#pragma unroll
            for (int nt = 0; nt < 4; ++nt)
#pragma unroll
                for (int reg = 0; reg < 4; ++reg) {
                    float p = exp2f(S[rt][nt][reg] - mnew[reg]);
                    S[rt][nt][reg] = p;
                    rs[reg] += p;
                }
#pragma unroll
            for (int reg = 0; reg < 4; ++reg) {
                float r = rs[reg];
                r += __shfl_xor(r, 1);
                r += __shfl_xor(r, 2);
                r += __shfl_xor(r, 4);
                r += __shfl_xor(r, 8);
                lrow[rt][reg] = lrow[rt][reg] * alpha[reg] + r;
            }
#pragma unroll
            for (int dt = 0; dt < 16; ++dt)
#pragma unroll
                for (int reg = 0; reg < 4; ++reg) Oacc[rt][dt][reg] *= alpha[reg];
            // P -> LDS (C-layout scatter; re-read below in A-layout)
#pragma unroll
            for (int nt = 0; nt < 4; ++nt)
#pragma unroll
                for (int reg = 0; reg < 4; ++reg)
                    p_lds[wave][(rt * 16 + quad * 4 + reg) * 72 + nt * 16 + n] = f2bf(S[rt][nt][reg]);
        }

        // ---- O += P V ----
#pragma unroll
        for (int kk = 0; kk < 2; ++kk) {
            short8 pa0 = *(const short8*)&p_lds[wave][(0 * 16 + n) * 72 + kk * 32 + quad * 8];
            short8 pa1 = *(const short8*)&p_lds[wave][(1 * 16 + n) * 72 + kk * 32 + quad * 8];
#pragma unroll
            for (int dt = 0; dt < 16; ++dt) {
                short8 bv = *(const short8*)&vt_lds[(dt * 16 + n) * 72 + kk * 32 + quad * 8];
                Oacc[0][dt] = MFMA16(pa0, bv, Oacc[0][dt]);
                Oacc[1][dt] = MFMA16(pa1, bv, Oacc[1][dt]);
            }
        }
    }

    // ---- epilogue: unnormalized partials ----
    const size_t obase = (size_t)blockIdx.y * N_Q * DV;
#pragma unroll
    for (int rt = 0; rt < 2; ++rt)
#pragma unroll
        for (int dt = 0; dt < 16; ++dt)
#pragma unroll
            for (int reg = 0; reg < 4; ++reg) {
                int gr = qrow0 + rt * 16 + quad * 4 + reg;
                Opart[obase + (size_t)gr * DV + dt * 16 + n] = Oacc[rt][dt][reg];
            }
    if (n == 0) {
#pragma unroll
        for (int rt = 0; rt < 2; ++rt)
#pragma unroll
            for (int reg = 0; reg < 4; ++reg) {
                int gr = qrow0 + rt * 16 + quad * 4 + reg;
                Mpart[blockIdx.y * N_Q + gr] = mrow[rt][reg];
                Lpart[blockIdx.y * N_Q + gr] = lrow[rt][reg];
            }
    }
}

// ---------------------------------------------------------------------------
// Combine split-K partials: out = sum_c w_c O_c / sum_c w_c l_c,
// w_c = exp2(m_c - max_c m_c). One block per row, one thread per d.
// ---------------------------------------------------------------------------
__global__ __launch_bounds__(256) void combine_kernel(
    const float* __restrict__ Opart, const float* __restrict__ Mpart,
    const float* __restrict__ Lpart, float* __restrict__ out, int nsplit)
{
    const int row = blockIdx.x, d = threadIdx.x;
    float mx = -3.4e38f;
    for (int c = 0; c < nsplit; ++c) mx = fmaxf(mx, Mpart[c * N_Q + row]);
    float L = 0.f, o = 0.f;
    for (int c = 0; c < nsplit; ++c) {
        float w = exp2f(Mpart[c * N_Q + row] - mx);
        L += w * Lpart[c * N_Q + row];
        o += w * Opart[((size_t)c * N_Q + row) * DV + d];
    }
    out[(size_t)row * DV + d] = o / L;
}

// ---------------------------------------------------------------------------
extern "C" void kernel_launch(void* const* d_in, const int* in_sizes, int n_in,
                              void* d_out, int out_size, void* d_ws, size_t ws_size,
                              hipStream_t stream)
{
    const float* main_feat  = (const float*)d_in[0];
    const float* other_feat = (const float*)d_in[1];
    const float* fix_feat   = (const float*)d_in[2];
    const void*  mask       = d_in[3];
    const float* Wq         = (const float*)d_in[4];
    const float* bq         = (const float*)d_in[5];
    const float* Wk         = (const float*)d_in[6];
    const float* bk         = (const float*)d_in[7];
    float* out = (float*)d_out;

    char* ws = (char*)d_ws;
    unsigned short* Qw = (unsigned short*)(ws);                       // 2 MB
    unsigned short* Kw = (unsigned short*)(ws + (1ull << 21));        // 2 MB
    unsigned short* Vt = (unsigned short*)(ws + (2ull << 21));        // 4 MB
    int* flag = (int*)(ws + (4ull << 21));
    float* Mpart = (float*)(ws + (4ull << 21) + 256);

    const size_t base = (4ull << 21) + 256;
    auto need = [&](int ns) {
        return base + (size_t)ns * N_Q * 4 * 2 + (size_t)ns * N_Q * DV * 4;
    };
    int nsplit = 1;
    if (ws_size >= need(8)) nsplit = 8;
    else if (ws_size >= need(4)) nsplit = 4;
    else if (ws_size >= need(2)) nsplit = 2;

    float* Lpart = Mpart + (size_t)nsplit * N_Q;
    float* Opart = Lpart + (size_t)nsplit * N_Q;

    hipLaunchKernelGGL(detect_mask_kernel, dim3(1), dim3(64), 0, stream,
                       (const unsigned int*)mask, flag);
    hipLaunchKernelGGL(proj_kernel, dim3(128, 2), dim3(256), 0, stream,
                       main_feat, Wq, bq, other_feat, Wk, bk, Qw, Kw);
    hipLaunchKernelGGL(build_vt_kernel, dim3(128, 4), dim3(256), 0, stream,
                       other_feat, fix_feat, Vt);
    hipLaunchKernelGGL(flash_kernel, dim3(64, nsplit), dim3(256), 0, stream,
                       Qw, Kw, Vt, mask, flag, Opart, Mpart, Lpart, nsplit);
    hipLaunchKernelGGL(combine_kernel, dim3(N_Q), dim3(256), 0, stream,
                       Opart, Mpart, Lpart, out, nsplit);
}

// Round 2
// 599.712 us; speedup vs baseline: 1.4573x; 1.4573x over previous
//
#include <hip/hip_runtime.h>
#include <hip/hip_bf16.h>
#include <stdint.h>

typedef __attribute__((ext_vector_type(8))) short short8;
typedef __attribute__((ext_vector_type(4))) float floatx4;

#define MFMA16(a, b, c) __builtin_amdgcn_mfma_f32_16x16x32_bf16(a, b, c, 0, 0, 0)

constexpr int N_Q  = 8192;
constexpr int M_KV = 8192;
constexpr int DMID = 128;
constexpr int DV   = 256;
constexpr int MWORDS = M_KV / 64;   // 128 u64 words per mask row

__device__ __forceinline__ unsigned short f2bf(float x) {
    unsigned u = __float_as_uint(x);
    u += 0x7fffu + ((u >> 16) & 1u);
    return (unsigned short)(u >> 16);
}

__device__ __forceinline__ short8 cvt_f8_bf8(float4 a, float4 b) {
    short8 r;
    r[0] = (short)f2bf(a.x); r[1] = (short)f2bf(a.y);
    r[2] = (short)f2bf(a.z); r[3] = (short)f2bf(a.w);
    r[4] = (short)f2bf(b.x); r[5] = (short)f2bf(b.y);
    r[6] = (short)f2bf(b.z); r[7] = (short)f2bf(b.w);
    return r;
}

// ---------------------------------------------------------------------------
// Mask dtype detection: 0 = int32 {0,1}, 1 = uint8 {0,1}, 2 = float32 {0,1}
// ---------------------------------------------------------------------------
__global__ void detect_mask_kernel(const unsigned int* __restrict__ mw, int* __restrict__ flag) {
    int t = threadIdx.x;
    unsigned w = mw[t];
    bool isf = (w == 0x3f800000u);
    bool isb = (w > 1u) && !isf;
    unsigned long long bf = __ballot(isf);
    unsigned long long bb = __ballot(isb);
    if (t == 0) *flag = bf ? 2 : (bb ? 1 : 0);
}

// ---------------------------------------------------------------------------
// Pack mask -> 1 bit per element. Word w covers row = w/MWORDS,
// cols (w%MWORDS)*64 .. +63; bit i = mask[w*64+i] != 0.
// ---------------------------------------------------------------------------
__global__ __launch_bounds__(256) void pack_mask_kernel(
    const void* __restrict__ mask, const int* __restrict__ flagp,
    unsigned long long* __restrict__ Mb)
{
    const int w = blockIdx.x * 256 + threadIdx.x;
    const int f = *flagp;
    unsigned long long bits = 0;
    if (f == 1) {   // uint8
        const uint4* p = (const uint4*)((const unsigned char*)mask + (size_t)w * 64);
#pragma unroll
        for (int i = 0; i < 4; ++i) {
            uint4 v = p[i];
            unsigned x[4] = {v.x, v.y, v.z, v.w};
#pragma unroll
            for (int j = 0; j < 4; ++j)
#pragma unroll
                for (int b = 0; b < 4; ++b)
                    bits |= (unsigned long long)(((x[j] >> (b * 8)) & 0xffu) != 0) << (i * 16 + j * 4 + b);
        }
    } else {        // int32 or float32 {0,1}: nonzero test on raw bits works
        const uint4* p = (const uint4*)((const unsigned int*)mask + (size_t)w * 64);
#pragma unroll
        for (int i = 0; i < 16; ++i) {
            uint4 v = p[i];
            bits |= (unsigned long long)(v.x != 0) << (i * 4 + 0);
            bits |= (unsigned long long)(v.y != 0) << (i * 4 + 1);
            bits |= (unsigned long long)(v.z != 0) << (i * 4 + 2);
            bits |= (unsigned long long)(v.w != 0) << (i * 4 + 3);
        }
    }
    Mb[w] = bits;
}

// ---------------------------------------------------------------------------
// Projections: dst[row,0:128] = src[row,0:256] @ W[128,256]^T + bias, bf16 out.
// ---------------------------------------------------------------------------
__global__ __launch_bounds__(256) void proj_kernel(
    const float* __restrict__ main_feat, const float* __restrict__ Wq, const float* __restrict__ bq,
    const float* __restrict__ other_feat, const float* __restrict__ Wk, const float* __restrict__ bk,
    unsigned short* __restrict__ Qw, unsigned short* __restrict__ Kw)
{
    const float* src;  const float* W;  const float* bias;  unsigned short* dst;
    if (blockIdx.y == 0) { src = main_feat;  W = Wq; bias = bq; dst = Qw; }
    else                 { src = other_feat; W = Wk; bias = bk; dst = Kw; }

    const int wave = threadIdx.x >> 6, lane = threadIdx.x & 63;
    const int n = lane & 15, quad = lane >> 4;
    const int row0 = blockIdx.x * 64 + wave * 16;

    short8 a[8];
    const float* ap = src + (size_t)(row0 + n) * 256 + quad * 8;
#pragma unroll
    for (int ks = 0; ks < 8; ++ks) {
        float4 x0 = *(const float4*)(ap + ks * 32);
        float4 x1 = *(const float4*)(ap + ks * 32 + 4);
        a[ks] = cvt_f8_bf8(x0, x1);
    }

    floatx4 acc[8];
#pragma unroll
    for (int nt = 0; nt < 8; ++nt) acc[nt] = floatx4{0.f, 0.f, 0.f, 0.f};

#pragma unroll
    for (int nt = 0; nt < 8; ++nt) {
        const float* wp = W + (size_t)(nt * 16 + n) * 256 + quad * 8;
#pragma unroll
        for (int ks = 0; ks < 8; ++ks) {
            float4 w0 = *(const float4*)(wp + ks * 32);
            float4 w1 = *(const float4*)(wp + ks * 32 + 4);
            short8 b = cvt_f8_bf8(w0, w1);
            acc[nt] = MFMA16(a[ks], b, acc[nt]);
        }
    }

#pragma unroll
    for (int nt = 0; nt < 8; ++nt) {
        float bb = bias[nt * 16 + n];
#pragma unroll
        for (int reg = 0; reg < 4; ++reg) {
            int r = row0 + quad * 4 + reg;
            dst[(size_t)r * DMID + nt * 16 + n] = f2bf(acc[nt][reg] + bb);
        }
    }
}

// ---------------------------------------------------------------------------
// Vt[d][m] = fix[m] * other[m][d], bf16 (transposed for PV B-fragments).
// ---------------------------------------------------------------------------
__global__ __launch_bounds__(256) void build_vt_kernel(
    const float* __restrict__ other_feat, const float* __restrict__ fix_feat,
    unsigned short* __restrict__ Vt)
{
    __shared__ unsigned short tile[64 * 72];
    const int t = threadIdx.x;
    const int m0 = blockIdx.x * 64, d0 = blockIdx.y * 64;

#pragma unroll
    for (int r = 0; r < 4; ++r) {
        int idx = r * 256 + t;
        int ml = idx >> 4, dl4 = (idx & 15) * 4;
        float4 v = *(const float4*)(other_feat + (size_t)(m0 + ml) * 256 + d0 + dl4);
        float f = fix_feat[m0 + ml];
        tile[(dl4 + 0) * 72 + ml] = f2bf(v.x * f);
        tile[(dl4 + 1) * 72 + ml] = f2bf(v.y * f);
        tile[(dl4 + 2) * 72 + ml] = f2bf(v.z * f);
        tile[(dl4 + 3) * 72 + ml] = f2bf(v.w * f);
    }
    __syncthreads();
#pragma unroll
    for (int r = 0; r < 8; ++r) {
        int dl = r * 8 + (t >> 5);
        int ml = (t & 31) * 2;
        unsigned int v0 = tile[dl * 72 + ml];
        unsigned int v1 = tile[dl * 72 + ml + 1];
        *(unsigned int*)(Vt + (size_t)(d0 + dl) * M_KV + m0 + ml) = v0 | (v1 << 16);
    }
}

// ---------------------------------------------------------------------------
// Flash attention with split-K over M. 256 thr (4 waves x 32 Q rows),
// BM=128, BN=64, 16x16x32 bf16 MFMA. Bit-packed mask. XCD swizzle: all
// blocks of one M-chunk land on one XCD (linear%8 -> XCD assumption) so
// K-chunk + Vt-chunk + mask bits stay L2-resident.
// ---------------------------------------------------------------------------
__global__ __launch_bounds__(256) void flash_kernel(
    const unsigned short* __restrict__ Qw, const unsigned short* __restrict__ Kw,
    const unsigned short* __restrict__ Vt, const unsigned long long* __restrict__ Mb,
    float* __restrict__ Opart, float* __restrict__ Mpart, float* __restrict__ Lpart,
    int nsplit, int lgNs)
{
    __shared__ __align__(16) unsigned short k_lds[64 * 136];
    __shared__ __align__(16) unsigned short vt_lds[256 * 72];
    __shared__ __align__(16) unsigned short p_lds[4][32 * 72];

    const int L = blockIdx.x + gridDim.x * blockIdx.y;
    const int ly = L & (nsplit - 1);      // M-chunk id == XCD id (for nsplit=8)
    const int lx = L >> lgNs;             // Q-block id
    const int chunkLen = M_KV >> lgNs;
    const int mBeg = ly * chunkLen;
    const int tid = threadIdx.x;
    const int wave = tid >> 6, lane = tid & 63, n = lane & 15, quad = lane >> 4;
    const int qrow0 = lx * 128 + wave * 32;
    constexpr float SC = 0.08838834764831845f * 1.4426950408889634f; // scale*log2(e)
    constexpr float MASKV = -3.0e30f;

    short8 qf[2][4];
#pragma unroll
    for (int rt = 0; rt < 2; ++rt)
#pragma unroll
        for (int ks = 0; ks < 4; ++ks)
            qf[rt][ks] = *(const short8*)(Qw + (size_t)(qrow0 + rt * 16 + n) * DMID + ks * 32 + quad * 8);

    floatx4 Oacc[2][16];
#pragma unroll
    for (int rt = 0; rt < 2; ++rt)
#pragma unroll
        for (int dt = 0; dt < 16; ++dt) Oacc[rt][dt] = floatx4{0.f, 0.f, 0.f, 0.f};

    float mrow[2][4], lrow[2][4];
#pragma unroll
    for (int rt = 0; rt < 2; ++rt)
#pragma unroll
        for (int reg = 0; reg < 4; ++reg) { mrow[rt][reg] = -__builtin_inff(); lrow[rt][reg] = 0.f; }

    const int iters = chunkLen / 64;
    for (int it = 0; it < iters; ++it) {
        const int m0 = mBeg + it * 64;
        __syncthreads();
#pragma unroll
        for (int r = 0; r < 4; ++r) {
            int idx = r * 256 + tid; int kr = idx >> 4, kc = idx & 15;
            *(short8*)&k_lds[kr * 136 + kc * 8] =
                *(const short8*)(Kw + (size_t)(m0 + kr) * DMID + kc * 8);
        }
#pragma unroll
        for (int r = 0; r < 8; ++r) {
            int idx = r * 256 + tid; int vr = idx >> 3, vc = idx & 7;
            *(short8*)&vt_lds[vr * 72 + vc * 8] =
                *(const short8*)(Vt + (size_t)vr * M_KV + m0 + vc * 8);
        }
        // mask bit words (issued early to overlap with staging + QK^T)
        unsigned long long wbits[2][4];
#pragma unroll
        for (int rt = 0; rt < 2; ++rt)
#pragma unroll
            for (int reg = 0; reg < 4; ++reg)
                wbits[rt][reg] = Mb[(size_t)(qrow0 + rt * 16 + quad * 4 + reg) * MWORDS + (m0 >> 6)];
        __syncthreads();

        // ---- S = Q K^T ----
        floatx4 S[2][4];
#pragma unroll
        for (int rt = 0; rt < 2; ++rt)
#pragma unroll
            for (int nt = 0; nt < 4; ++nt) S[rt][nt] = floatx4{0.f, 0.f, 0.f, 0.f};

#pragma unroll
        for (int nt = 0; nt < 4; ++nt) {
            const int kb = (nt * 16 + n) * 136 + quad * 8;
            short8 b0 = *(const short8*)&k_lds[kb];
            short8 b1 = *(const short8*)&k_lds[kb + 32];
            short8 b2 = *(const short8*)&k_lds[kb + 64];
            short8 b3 = *(const short8*)&k_lds[kb + 96];
            S[0][nt] = MFMA16(qf[0][0], b0, S[0][nt]);
            S[0][nt] = MFMA16(qf[0][1], b1, S[0][nt]);
            S[0][nt] = MFMA16(qf[0][2], b2, S[0][nt]);
            S[0][nt] = MFMA16(qf[0][3], b3, S[0][nt]);
            S[1][nt] = MFMA16(qf[1][0], b0, S[1][nt]);
            S[1][nt] = MFMA16(qf[1][1], b1, S[1][nt]);
            S[1][nt] = MFMA16(qf[1][2], b2, S[1][nt]);
            S[1][nt] = MFMA16(qf[1][3], b3, S[1][nt]);
        }

        // ---- apply mask + scale (bit nt*16+n of wbits[rt][reg]) ----
#pragma unroll
        for (int rt = 0; rt < 2; ++rt)
#pragma unroll
            for (int reg = 0; reg < 4; ++reg) {
                unsigned long long x = wbits[rt][reg] >> n;
                unsigned lo = (unsigned)x, hi = (unsigned)(x >> 32);
                S[rt][0][reg] = (lo & 1u)         ? MASKV : S[rt][0][reg] * SC;
                S[rt][1][reg] = ((lo >> 16) & 1u) ? MASKV : S[rt][1][reg] * SC;
                S[rt][2][reg] = (hi & 1u)         ? MASKV : S[rt][2][reg] * SC;
                S[rt][3][reg] = ((hi >> 16) & 1u) ? MASKV : S[rt][3][reg] * SC;
            }

        // ---- online softmax ----
#pragma unroll
        for (int rt = 0; rt < 2; ++rt) {
            float mnew[4], alpha[4];
            bool changed = false;
#pragma unroll
            for (int reg = 0; reg < 4; ++reg) {
                float v = fmaxf(fmaxf(S[rt][0][reg], S[rt][1][reg]),
                                fmaxf(S[rt][2][reg], S[rt][3][reg]));
                v = fmaxf(v, __shfl_xor(v, 1));
                v = fmaxf(v, __shfl_xor(v, 2));
                v = fmaxf(v, __shfl_xor(v, 4));
                v = fmaxf(v, __shfl_xor(v, 8));
                mnew[reg] = fmaxf(mrow[rt][reg], v);
                changed = changed || (mnew[reg] > mrow[rt][reg]);
                alpha[reg] = exp2f(mrow[rt][reg] - mnew[reg]);
                mrow[rt][reg] = mnew[reg];
            }
            float rs[4] = {0.f, 0.f, 0.f, 0.f};
#pragma unroll
            for (int nt = 0; nt < 4; ++nt)
#pragma unroll
                for (int reg = 0; reg < 4; ++reg) {
                    float p = exp2f(S[rt][nt][reg] - mnew[reg]);
                    S[rt][nt][reg] = p;
                    rs[reg] += p;
                }
#pragma unroll
            for (int reg = 0; reg < 4; ++reg) {
                float r = rs[reg];
                r += __shfl_xor(r, 1);
                r += __shfl_xor(r, 2);
                r += __shfl_xor(r, 4);
                r += __shfl_xor(r, 8);
                lrow[rt][reg] = lrow[rt][reg] * alpha[reg] + r;
            }
            if (__any(changed)) {
#pragma unroll
                for (int dt = 0; dt < 16; ++dt)
#pragma unroll
                    for (int reg = 0; reg < 4; ++reg) Oacc[rt][dt][reg] *= alpha[reg];
            }
#pragma unroll
            for (int nt = 0; nt < 4; ++nt)
#pragma unroll
                for (int reg = 0; reg < 4; ++reg)
                    p_lds[wave][(rt * 16 + quad * 4 + reg) * 72 + nt * 16 + n] = f2bf(S[rt][nt][reg]);
        }

        // ---- O += P V ----
#pragma unroll
        for (int kk = 0; kk < 2; ++kk) {
            short8 pa0 = *(const short8*)&p_lds[wave][(0 * 16 + n) * 72 + kk * 32 + quad * 8];
            short8 pa1 = *(const short8*)&p_lds[wave][(1 * 16 + n) * 72 + kk * 32 + quad * 8];
#pragma unroll
            for (int dt = 0; dt < 16; ++dt) {
                short8 bv = *(const short8*)&vt_lds[(dt * 16 + n) * 72 + kk * 32 + quad * 8];
                Oacc[0][dt] = MFMA16(pa0, bv, Oacc[0][dt]);
                Oacc[1][dt] = MFMA16(pa1, bv, Oacc[1][dt]);
            }
        }
    }

    // ---- epilogue ----
    const size_t obase = (size_t)ly * N_Q * DV;
#pragma unroll
    for (int rt = 0; rt < 2; ++rt)
#pragma unroll
        for (int dt = 0; dt < 16; ++dt)
#pragma unroll
            for (int reg = 0; reg < 4; ++reg) {
                int gr = qrow0 + rt * 16 + quad * 4 + reg;
                Opart[obase + (size_t)gr * DV + dt * 16 + n] = Oacc[rt][dt][reg];
            }
    if (n == 0) {
#pragma unroll
        for (int rt = 0; rt < 2; ++rt)
#pragma unroll
            for (int reg = 0; reg < 4; ++reg) {
                int gr = qrow0 + rt * 16 + quad * 4 + reg;
                Mpart[ly * N_Q + gr] = mrow[rt][reg];
                Lpart[ly * N_Q + gr] = lrow[rt][reg];
            }
    }
}

// ---------------------------------------------------------------------------
__global__ __launch_bounds__(256) void combine_kernel(
    const float* __restrict__ Opart, const float* __restrict__ Mpart,
    const float* __restrict__ Lpart, float* __restrict__ out, int nsplit)
{
    const int row = blockIdx.x, d = threadIdx.x;
    float mx = -3.4e38f;
    for (int c = 0; c < nsplit; ++c) mx = fmaxf(mx, Mpart[c * N_Q + row]);
    float L = 0.f, o = 0.f;
    for (int c = 0; c < nsplit; ++c) {
        float w = exp2f(Mpart[c * N_Q + row] - mx);
        L += w * Lpart[c * N_Q + row];
        o += w * Opart[((size_t)c * N_Q + row) * DV + d];
    }
    out[(size_t)row * DV + d] = o / L;
}

// ---------------------------------------------------------------------------
extern "C" void kernel_launch(void* const* d_in, const int* in_sizes, int n_in,
                              void* d_out, int out_size, void* d_ws, size_t ws_size,
                              hipStream_t stream)
{
    const float* main_feat  = (const float*)d_in[0];
    const float* other_feat = (const float*)d_in[1];
    const float* fix_feat   = (const float*)d_in[2];
    const void*  mask       = d_in[3];
    const float* Wq         = (const float*)d_in[4];
    const float* bq         = (const float*)d_in[5];
    const float* Wk         = (const float*)d_in[6];
    const float* bk         = (const float*)d_in[7];
    float* out = (float*)d_out;

    char* ws = (char*)d_ws;
    unsigned short* Qw = (unsigned short*)(ws);                         // 2 MB
    unsigned short* Kw = (unsigned short*)(ws + (1ull << 21));          // 2 MB
    unsigned short* Vt = (unsigned short*)(ws + (2ull << 21));          // 4 MB
    int* flag = (int*)(ws + (8ull << 20));
    unsigned long long* Mb = (unsigned long long*)(ws + (8ull << 20) + 1024);  // 8 MB
    float* Mpart = (float*)(ws + (16ull << 20) + 2048);

    const size_t base = (16ull << 20) + 2048;
    auto need = [&](int ns) {
        return base + (size_t)ns * N_Q * 4 * 2 + (size_t)ns * N_Q * DV * 4;
    };
    int nsplit = 1, lgNs = 0;
    if (ws_size >= need(8))      { nsplit = 8; lgNs = 3; }
    else if (ws_size >= need(4)) { nsplit = 4; lgNs = 2; }
    else if (ws_size >= need(2)) { nsplit = 2; lgNs = 1; }

    float* Lpart = Mpart + (size_t)nsplit * N_Q;
    float* Opart = Lpart + (size_t)nsplit * N_Q;

    hipLaunchKernelGGL(detect_mask_kernel, dim3(1), dim3(64), 0, stream,
                       (const unsigned int*)mask, flag);
    hipLaunchKernelGGL(pack_mask_kernel, dim3(N_Q * MWORDS / 256), dim3(256), 0, stream,
                       mask, flag, Mb);
    hipLaunchKernelGGL(proj_kernel, dim3(128, 2), dim3(256), 0, stream,
                       main_feat, Wq, bq, other_feat, Wk, bk, Qw, Kw);
    hipLaunchKernelGGL(build_vt_kernel, dim3(128, 4), dim3(256), 0, stream,
                       other_feat, fix_feat, Vt);
    hipLaunchKernelGGL(flash_kernel, dim3(64, nsplit), dim3(256), 0, stream,
                       Qw, Kw, Vt, Mb, Opart, Mpart, Lpart, nsplit, lgNs);
    hipLaunchKernelGGL(combine_kernel, dim3(N_Q), dim3(256), 0, stream,
                       Opart, Mpart, Lpart, out, nsplit);
}